// Round 1
// baseline (9331.316 us; speedup 1.0000x reference)
//
#include <hip/hip_runtime.h>

#define N_NODES 50000
#define N_EDGES 400000
#define F_IN    128
#define HID     64
#define HEADS   4
#define HEADC   16
#define C_CLS   10
#define HC      (HEADS * C_CLS)   // 40
#define M_DIM   (HID * C_CLS)     // 640 = HEADS*HEADC*C_CLS
#define CST     1e-5f

// -------------------- projections: x -> Q, Kf0, V0 --------------------
// one block (64 threads) per node
__global__ __launch_bounds__(64) void proj_kernel(
    const float* __restrict__ feat,
    const float* __restrict__ W_in, const float* __restrict__ b_in,
    const float* __restrict__ W_q,  const float* __restrict__ b_q,
    const float* __restrict__ W_k,  const float* __restrict__ b_k,
    const float* __restrict__ W_v,  const float* __restrict__ b_v,
    float* __restrict__ Q, float* __restrict__ Kf0, float* __restrict__ V0)
{
    const int n = blockIdx.x;
    const int t = threadIdx.x;
    __shared__ float sf[F_IN];
    __shared__ float sx[HID];

    sf[t]      = feat[(size_t)n * F_IN + t];
    sf[t + 64] = feat[(size_t)n * F_IN + t + 64];
    __syncthreads();

    // x = relu(feat @ W_in^T + b_in)
    float acc = b_in[t];
    const float* w = W_in + (size_t)t * F_IN;
    #pragma unroll 8
    for (int k = 0; k < F_IN; ++k) acc += sf[k] * w[k];
    sx[t] = fmaxf(acc, 0.0f);
    __syncthreads();

    // Q, K: 1 + elu(z) = z+1 (z>0) else exp(z)
    float aq = b_q[t], ak = b_k[t];
    const float* wq = W_q + (size_t)t * HID;
    const float* wk = W_k + (size_t)t * HID;
    #pragma unroll 8
    for (int k = 0; k < HID; ++k) {
        float xv = sx[k];
        aq += xv * wq[k];
        ak += xv * wk[k];
    }
    Q  [(size_t)n * HID + t] = (aq > 0.0f) ? (aq + 1.0f) : expf(aq);
    Kf0[(size_t)n * HID + t] = (ak > 0.0f) ? (ak + 1.0f) : expf(ak);

    if (t < HC) {
        float av = b_v[t];
        const float* wv = W_v + (size_t)t * HID;
        #pragma unroll 8
        for (int k = 0; k < HID; ++k) av += sx[k] * wv[k];
        V0[(size_t)n * HC + t] = av;
    }
}

// -------------------- hop 1: edge-wise --------------------
// wave (64 lanes) per edge; lane = h*16+i. 4 edges per 256-thread block.
// Builds M1 (needed for hop2), Kf1, and edge-wise H1/Cd1.
__global__ __launch_bounds__(256) void hop1_kernel(
    const int* __restrict__ erow, const int* __restrict__ ecol,
    const float* __restrict__ Q, const float* __restrict__ Kf0,
    const float* __restrict__ V0,
    float* __restrict__ Kf1, float* __restrict__ M1,
    float* __restrict__ H1, float* __restrict__ Cd1)
{
    const int sub  = threadIdx.x >> 6;          // edge slot in block
    const int lane = threadIdx.x & 63;          // (h,i)
    const int e    = blockIdx.x * 4 + sub;      // grid sized exactly
    const int s = erow[e];
    const int n = ecol[e];

    __shared__ float sv[4][HC];
    if (lane < HC) sv[sub][lane] = V0[(size_t)s * HC + lane];

    const float kf = Kf0[(size_t)s * HID + lane];
    const float q  = Q  [(size_t)n * HID + lane];
    __syncthreads();

    // alpha_h = Q[n,h,:] . Kf0[s,h,:]  (reduce within 16-lane group)
    float p = q * kf;
    p += __shfl_xor(p, 1);
    p += __shfl_xor(p, 2);
    p += __shfl_xor(p, 4);
    p += __shfl_xor(p, 8);
    const float alpha = p;

    const int h = lane >> 4;
    const int r = lane & 15;

    if (r == 0)     atomicAdd(&Cd1[(size_t)n * HEADS + h], alpha);
    if (r < C_CLS)  atomicAdd(&H1[(size_t)n * HC + h * C_CLS + r],
                              alpha * sv[sub][h * C_CLS + r]);
    atomicAdd(&Kf1[(size_t)n * HID + lane], kf);

    float* m = M1 + (size_t)n * M_DIM + lane * C_CLS;
    #pragma unroll
    for (int j = 0; j < C_CLS; ++j)
        atomicAdd(&m[j], kf * sv[sub][h * C_CLS + j]);
}

// -------------------- hop 2: edge-wise, M2 never materialized --------------------
__global__ __launch_bounds__(256) void hop2_kernel(
    const int* __restrict__ erow, const int* __restrict__ ecol,
    const float* __restrict__ Q, const float* __restrict__ Kf1,
    const float* __restrict__ M1,
    float* __restrict__ H2, float* __restrict__ Cd2)
{
    const int sub  = threadIdx.x >> 6;
    const int lane = threadIdx.x & 63;
    const int e    = blockIdx.x * 4 + sub;
    const int s = erow[e];
    const int n = ecol[e];

    const float q   = Q  [(size_t)n * HID + lane];
    const float kf1 = Kf1[(size_t)s * HID + lane];

    const int h = lane >> 4;
    const int r = lane & 15;

    // Cd2 contribution: Q[n,h,:] . Kf1[s,h,:]
    float pc = q * kf1;
    pc += __shfl_xor(pc, 1);
    pc += __shfl_xor(pc, 2);
    pc += __shfl_xor(pc, 4);
    pc += __shfl_xor(pc, 8);
    if (r == 0) atomicAdd(&Cd2[(size_t)n * HEADS + h], pc);

    // H2 contribution: sum_i Q[n,h,i] * M1[s,h,i,j]
    const float* m = M1 + (size_t)s * M_DIM + lane * C_CLS;
    float pj[C_CLS];
    #pragma unroll
    for (int j = 0; j < C_CLS; ++j) pj[j] = q * m[j];
    #pragma unroll
    for (int j = 0; j < C_CLS; ++j) {
        pj[j] += __shfl_xor(pj[j], 1);
        pj[j] += __shfl_xor(pj[j], 2);
        pj[j] += __shfl_xor(pj[j], 4);
        pj[j] += __shfl_xor(pj[j], 8);
    }
    if (r < C_CLS) {
        float val = 0.0f;                  // static-index select (avoid scratch)
        #pragma unroll
        for (int j = 0; j < C_CLS; ++j) val = (r == j) ? pj[j] : val;
        atomicAdd(&H2[(size_t)n * HC + h * C_CLS + r], val);
    }
}

// -------------------- combine + output projection --------------------
__global__ __launch_bounds__(256) void combine_kernel(
    const float* __restrict__ V0,
    const float* __restrict__ H1, const float* __restrict__ Cd1,
    const float* __restrict__ H2, const float* __restrict__ Cd2,
    const float* __restrict__ hopwise, const float* __restrict__ headwise,
    const float* __restrict__ W_out, const float* __restrict__ b_out,
    float* __restrict__ out)
{
    const int n = blockIdx.x * blockDim.x + threadIdx.x;
    if (n >= N_NODES) return;

    // layerwise = softmax(headwise, axis=0)  (over heads, per hop)
    float hv[HEADS][2];
    float m0 = -1e30f, m1 = -1e30f;
    #pragma unroll
    for (int h = 0; h < HEADS; ++h) {
        hv[h][0] = headwise[h * 2 + 0];
        hv[h][1] = headwise[h * 2 + 1];
        m0 = fmaxf(m0, hv[h][0]);
        m1 = fmaxf(m1, hv[h][1]);
    }
    float s0 = 0.0f, s1 = 0.0f;
    float e0[HEADS], e1[HEADS];
    #pragma unroll
    for (int h = 0; h < HEADS; ++h) {
        e0[h] = expf(hv[h][0] - m0); s0 += e0[h];
        e1[h] = expf(hv[h][1] - m1); s1 += e1[h];
    }
    const float hw0 = hopwise[0];
    float g1[HEADS], g2[HEADS];
    #pragma unroll
    for (int h = 0; h < HEADS; ++h) {
        g1[h] = hopwise[1] * e0[h] / s0;
        g2[h] = hopwise[2] * e1[h] / s1;
    }

    float hidden[HC];
    #pragma unroll
    for (int h = 0; h < HEADS; ++h) {
        const float icd1 = 1.0f / (Cd1[(size_t)n * HEADS + h] + CST);
        const float icd2 = 1.0f / (Cd2[(size_t)n * HEADS + h] + CST);
        #pragma unroll
        for (int j = 0; j < C_CLS; ++j) {
            const int idx = h * C_CLS + j;
            hidden[idx] = hw0 * V0[(size_t)n * HC + idx]
                        + g1[h] * H1[(size_t)n * HC + idx] * icd1
                        + g2[h] * H2[(size_t)n * HC + idx] * icd2;
        }
    }

    #pragma unroll
    for (int c = 0; c < C_CLS; ++c) {
        float acc = b_out[c];
        const float* w = W_out + c * HC;
        #pragma unroll
        for (int k = 0; k < HC; ++k) acc += w[k] * hidden[k];
        out[(size_t)n * C_CLS + c] = acc;
    }
}

// -------------------- launch --------------------
extern "C" void kernel_launch(void* const* d_in, const int* in_sizes, int n_in,
                              void* d_out, int out_size, void* d_ws, size_t ws_size,
                              hipStream_t stream)
{
    const float* feat     = (const float*)d_in[0];
    const int*   eidx     = (const int*)  d_in[1];   // [2, E] int32
    const float* W_in     = (const float*)d_in[2];
    const float* b_in     = (const float*)d_in[3];
    const float* W_q      = (const float*)d_in[4];
    const float* b_q      = (const float*)d_in[5];
    const float* W_k      = (const float*)d_in[6];
    const float* b_k      = (const float*)d_in[7];
    const float* W_v      = (const float*)d_in[8];
    const float* b_v      = (const float*)d_in[9];
    const float* W_out    = (const float*)d_in[10];
    const float* b_out    = (const float*)d_in[11];
    const float* hopwise  = (const float*)d_in[12];
    const float* headwise = (const float*)d_in[13];
    float* out = (float*)d_out;

    const int* erow = eidx;
    const int* ecol = eidx + N_EDGES;

    // workspace layout (floats)
    float* ws = (float*)d_ws;
    size_t off = 0;
    float* Q    = ws + off; off += (size_t)N_NODES * HID;    // 64N
    float* Kf0  = ws + off; off += (size_t)N_NODES * HID;    // 64N
    float* V0   = ws + off; off += (size_t)N_NODES * HC;     // 40N
    float* zero_base = ws + off;
    float* Kf1  = ws + off; off += (size_t)N_NODES * HID;    // 64N
    float* M1   = ws + off; off += (size_t)N_NODES * M_DIM;  // 640N
    float* H1   = ws + off; off += (size_t)N_NODES * HC;     // 40N
    float* Cd1  = ws + off; off += (size_t)N_NODES * HEADS;  // 4N
    float* H2   = ws + off; off += (size_t)N_NODES * HC;     // 40N
    float* Cd2  = ws + off; off += (size_t)N_NODES * HEADS;  // 4N
    const size_t zero_bytes = (size_t)(ws + off - zero_base) * sizeof(float);

    hipMemsetAsync(zero_base, 0, zero_bytes, stream);

    proj_kernel<<<N_NODES, 64, 0, stream>>>(
        feat, W_in, b_in, W_q, b_q, W_k, b_k, W_v, b_v, Q, Kf0, V0);

    hop1_kernel<<<N_EDGES / 4, 256, 0, stream>>>(
        erow, ecol, Q, Kf0, V0, Kf1, M1, H1, Cd1);

    hop2_kernel<<<N_EDGES / 4, 256, 0, stream>>>(
        erow, ecol, Q, Kf1, M1, H2, Cd2);

    combine_kernel<<<(N_NODES + 255) / 256, 256, 0, stream>>>(
        V0, H1, Cd1, H2, Cd2, hopwise, headwise, W_out, b_out, out);
}

// Round 2
// 821.204 us; speedup vs baseline: 11.3630x; 11.3630x over previous
//
#include <hip/hip_runtime.h>

#define N_NODES 50000
#define N_EDGES 400000
#define F_IN    128
#define HID     64
#define HEADS   4
#define HEADC   16
#define C_CLS   10
#define HC      (HEADS * C_CLS)   // 40
#define M_DIM   (HID * C_CLS)     // 640
#define CST     1e-5f
#define SCAN_T  1024
#define SCAN_PER ((N_NODES + SCAN_T - 1) / SCAN_T)   // 49

// -------------------- projections: x -> Q, Kf0, V0 --------------------
__global__ __launch_bounds__(64) void proj_kernel(
    const float* __restrict__ feat,
    const float* __restrict__ W_in, const float* __restrict__ b_in,
    const float* __restrict__ W_q,  const float* __restrict__ b_q,
    const float* __restrict__ W_k,  const float* __restrict__ b_k,
    const float* __restrict__ W_v,  const float* __restrict__ b_v,
    float* __restrict__ Q, float* __restrict__ Kf0, float* __restrict__ V0)
{
    const int n = blockIdx.x;
    const int t = threadIdx.x;
    __shared__ float sf[F_IN];
    __shared__ float sx[HID];

    sf[t]      = feat[(size_t)n * F_IN + t];
    sf[t + 64] = feat[(size_t)n * F_IN + t + 64];
    __syncthreads();

    float acc = b_in[t];
    const float* w = W_in + (size_t)t * F_IN;
    #pragma unroll 8
    for (int k = 0; k < F_IN; ++k) acc += sf[k] * w[k];
    sx[t] = fmaxf(acc, 0.0f);
    __syncthreads();

    float aq = b_q[t], ak = b_k[t];
    const float* wq = W_q + (size_t)t * HID;
    const float* wk = W_k + (size_t)t * HID;
    #pragma unroll 8
    for (int k = 0; k < HID; ++k) {
        float xv = sx[k];
        aq += xv * wq[k];
        ak += xv * wk[k];
    }
    Q  [(size_t)n * HID + t] = (aq > 0.0f) ? (aq + 1.0f) : expf(aq);
    Kf0[(size_t)n * HID + t] = (ak > 0.0f) ? (ak + 1.0f) : expf(ak);

    if (t < HC) {
        float av = b_v[t];
        const float* wv = W_v + (size_t)t * HID;
        #pragma unroll 8
        for (int k = 0; k < HID; ++k) av += sx[k] * wv[k];
        V0[(size_t)n * HC + t] = av;
    }
}

// -------------------- CSR build --------------------
__global__ __launch_bounds__(256) void hist_kernel(
    const int* __restrict__ ecol, int* __restrict__ deg)
{
    const int e = blockIdx.x * 256 + threadIdx.x;
    if (e < N_EDGES) atomicAdd(&deg[ecol[e]], 1);
}

// single-block exclusive scan over 50K degrees -> rowptr, cursor
__global__ __launch_bounds__(SCAN_T) void scan_kernel(
    const int* __restrict__ deg, int* __restrict__ rowptr, int* __restrict__ cursor)
{
    __shared__ int part[SCAN_T];
    const int t = threadIdx.x;
    const int base = t * SCAN_PER;
    int s = 0;
    for (int i = 0; i < SCAN_PER; ++i) {
        int idx = base + i;
        if (idx < N_NODES) s += deg[idx];
    }
    part[t] = s;
    __syncthreads();
    // Hillis-Steele inclusive scan
    for (int off = 1; off < SCAN_T; off <<= 1) {
        int v = (t >= off) ? part[t - off] : 0;
        __syncthreads();
        part[t] += v;
        __syncthreads();
    }
    int run = (t == 0) ? 0 : part[t - 1];
    for (int i = 0; i < SCAN_PER; ++i) {
        int idx = base + i;
        if (idx < N_NODES) {
            rowptr[idx] = run;
            cursor[idx] = run;
            run += deg[idx];
        }
    }
}

__global__ __launch_bounds__(256) void scatter_kernel(
    const int* __restrict__ erow, const int* __restrict__ ecol,
    int* __restrict__ cursor, int* __restrict__ csr_src)
{
    const int e = blockIdx.x * 256 + threadIdx.x;
    if (e < N_EDGES) {
        const int pos = atomicAdd(&cursor[ecol[e]], 1);
        csr_src[pos] = erow[e];
    }
}

// -------------------- hop 1: gather, no atomics --------------------
// wave per node; lane = h*16+i. M1 layout: [n][j][64] for coalescing.
__global__ __launch_bounds__(256) void hop1_gather(
    const int* __restrict__ csr_src, const int* __restrict__ rowptr,
    const int* __restrict__ deg,
    const float* __restrict__ Q, const float* __restrict__ Kf0,
    const float* __restrict__ V0,
    float* __restrict__ Kf1, float* __restrict__ M1,
    float* __restrict__ H1, float* __restrict__ Cd1)
{
    const int sub  = threadIdx.x >> 6;
    const int lane = threadIdx.x & 63;
    const int n    = blockIdx.x * 4 + sub;
    if (n >= N_NODES) return;
    const int h = lane >> 4;
    const int r = lane & 15;

    const float q = Q[(size_t)n * HID + lane];
    float accM[C_CLS];
    #pragma unroll
    for (int j = 0; j < C_CLS; ++j) accM[j] = 0.0f;
    float accK = 0.0f, accH = 0.0f, accA = 0.0f;

    const int beg = rowptr[n];
    const int d   = deg[n];
    for (int e = 0; e < d; ++e) {
        const int s = csr_src[beg + e];
        const float kf = Kf0[(size_t)s * HID + lane];
        accK += kf;
        // alpha_h = Q[n,h,:] . Kf0[s,h,:]
        float p = q * kf;
        p += __shfl_xor(p, 1);
        p += __shfl_xor(p, 2);
        p += __shfl_xor(p, 4);
        p += __shfl_xor(p, 8);
        accA += p;
        const float* v = V0 + (size_t)s * HC + h * C_CLS;
        #pragma unroll
        for (int j = 0; j < C_CLS; ++j) {
            const float vj = v[j];
            accM[j] += kf * vj;
            accH = (j == r) ? (accH + p * vj) : accH;   // lane r<10 owns H1[h,r]
        }
    }

    Kf1[(size_t)n * HID + lane] = accK;
    float* m = M1 + (size_t)n * M_DIM;
    #pragma unroll
    for (int j = 0; j < C_CLS; ++j) m[j * HID + lane] = accM[j];  // coalesced
    if (r == 0)     Cd1[(size_t)n * HEADS + h] = accA;
    if (r < C_CLS)  H1 [(size_t)n * HC + h * C_CLS + r] = accH;
}

// -------------------- hop 2: gather; M2/Kf2 summed in registers --------------------
__global__ __launch_bounds__(256) void hop2_gather(
    const int* __restrict__ csr_src, const int* __restrict__ rowptr,
    const int* __restrict__ deg,
    const float* __restrict__ Q, const float* __restrict__ Kf1,
    const float* __restrict__ M1,
    float* __restrict__ H2, float* __restrict__ Cd2)
{
    const int sub  = threadIdx.x >> 6;
    const int lane = threadIdx.x & 63;
    const int n    = blockIdx.x * 4 + sub;
    if (n >= N_NODES) return;
    const int h = lane >> 4;
    const int r = lane & 15;

    const float q = Q[(size_t)n * HID + lane];
    float accM[C_CLS];
    #pragma unroll
    for (int j = 0; j < C_CLS; ++j) accM[j] = 0.0f;
    float accK = 0.0f;

    const int beg = rowptr[n];
    const int d   = deg[n];
    for (int e = 0; e < d; ++e) {
        const int s = csr_src[beg + e];
        accK += Kf1[(size_t)s * HID + lane];
        const float* m = M1 + (size_t)s * M_DIM;
        #pragma unroll
        for (int j = 0; j < C_CLS; ++j) accM[j] += m[j * HID + lane];  // coalesced
    }

    // Cd2 = Q[n,h,:] . Kf2[h,:]
    float pc = q * accK;
    pc += __shfl_xor(pc, 1);
    pc += __shfl_xor(pc, 2);
    pc += __shfl_xor(pc, 4);
    pc += __shfl_xor(pc, 8);
    if (r == 0) Cd2[(size_t)n * HEADS + h] = pc;

    // H2[h,j] = sum_i Q[n,h,i] * M2[h,i,j]
    float pj[C_CLS];
    #pragma unroll
    for (int j = 0; j < C_CLS; ++j) {
        pj[j] = q * accM[j];
        pj[j] += __shfl_xor(pj[j], 1);
        pj[j] += __shfl_xor(pj[j], 2);
        pj[j] += __shfl_xor(pj[j], 4);
        pj[j] += __shfl_xor(pj[j], 8);
    }
    if (r < C_CLS) {
        float val = 0.0f;
        #pragma unroll
        for (int j = 0; j < C_CLS; ++j) val = (r == j) ? pj[j] : val;
        H2[(size_t)n * HC + h * C_CLS + r] = val;
    }
}

// -------------------- combine + output projection --------------------
__global__ __launch_bounds__(256) void combine_kernel(
    const float* __restrict__ V0,
    const float* __restrict__ H1, const float* __restrict__ Cd1,
    const float* __restrict__ H2, const float* __restrict__ Cd2,
    const float* __restrict__ hopwise, const float* __restrict__ headwise,
    const float* __restrict__ W_out, const float* __restrict__ b_out,
    float* __restrict__ out)
{
    const int n = blockIdx.x * blockDim.x + threadIdx.x;
    if (n >= N_NODES) return;

    float hv[HEADS][2];
    float m0 = -1e30f, m1 = -1e30f;
    #pragma unroll
    for (int h = 0; h < HEADS; ++h) {
        hv[h][0] = headwise[h * 2 + 0];
        hv[h][1] = headwise[h * 2 + 1];
        m0 = fmaxf(m0, hv[h][0]);
        m1 = fmaxf(m1, hv[h][1]);
    }
    float s0 = 0.0f, s1 = 0.0f;
    float e0[HEADS], e1[HEADS];
    #pragma unroll
    for (int h = 0; h < HEADS; ++h) {
        e0[h] = expf(hv[h][0] - m0); s0 += e0[h];
        e1[h] = expf(hv[h][1] - m1); s1 += e1[h];
    }
    const float hw0 = hopwise[0];
    float g1[HEADS], g2[HEADS];
    #pragma unroll
    for (int h = 0; h < HEADS; ++h) {
        g1[h] = hopwise[1] * e0[h] / s0;
        g2[h] = hopwise[2] * e1[h] / s1;
    }

    float hidden[HC];
    #pragma unroll
    for (int h = 0; h < HEADS; ++h) {
        const float icd1 = 1.0f / (Cd1[(size_t)n * HEADS + h] + CST);
        const float icd2 = 1.0f / (Cd2[(size_t)n * HEADS + h] + CST);
        #pragma unroll
        for (int j = 0; j < C_CLS; ++j) {
            const int idx = h * C_CLS + j;
            hidden[idx] = hw0 * V0[(size_t)n * HC + idx]
                        + g1[h] * H1[(size_t)n * HC + idx] * icd1
                        + g2[h] * H2[(size_t)n * HC + idx] * icd2;
        }
    }

    #pragma unroll
    for (int c = 0; c < C_CLS; ++c) {
        float acc = b_out[c];
        const float* w = W_out + c * HC;
        #pragma unroll
        for (int k = 0; k < HC; ++k) acc += w[k] * hidden[k];
        out[(size_t)n * C_CLS + c] = acc;
    }
}

// -------------------- launch --------------------
extern "C" void kernel_launch(void* const* d_in, const int* in_sizes, int n_in,
                              void* d_out, int out_size, void* d_ws, size_t ws_size,
                              hipStream_t stream)
{
    const float* feat     = (const float*)d_in[0];
    const int*   eidx     = (const int*)  d_in[1];
    const float* W_in     = (const float*)d_in[2];
    const float* b_in     = (const float*)d_in[3];
    const float* W_q      = (const float*)d_in[4];
    const float* b_q      = (const float*)d_in[5];
    const float* W_k      = (const float*)d_in[6];
    const float* b_k      = (const float*)d_in[7];
    const float* W_v      = (const float*)d_in[8];
    const float* b_v      = (const float*)d_in[9];
    const float* W_out    = (const float*)d_in[10];
    const float* b_out    = (const float*)d_in[11];
    const float* hopwise  = (const float*)d_in[12];
    const float* headwise = (const float*)d_in[13];
    float* out = (float*)d_out;

    const int* erow = eidx;
    const int* ecol = eidx + N_EDGES;

    float* ws = (float*)d_ws;
    size_t off = 0;
    float* Q    = ws + off; off += (size_t)N_NODES * HID;
    float* Kf0  = ws + off; off += (size_t)N_NODES * HID;
    float* V0   = ws + off; off += (size_t)N_NODES * HC;
    float* Kf1  = ws + off; off += (size_t)N_NODES * HID;
    float* M1   = ws + off; off += (size_t)N_NODES * M_DIM;
    float* H1   = ws + off; off += (size_t)N_NODES * HC;
    float* Cd1  = ws + off; off += (size_t)N_NODES * HEADS;
    float* H2   = ws + off; off += (size_t)N_NODES * HC;
    float* Cd2  = ws + off; off += (size_t)N_NODES * HEADS;
    int* iws = (int*)(ws + off);
    int* deg     = iws;                 // N
    int* rowptr  = iws + N_NODES;       // N
    int* cursor  = iws + 2 * N_NODES;   // N
    int* csr_src = iws + 3 * N_NODES;   // E

    // only the degree histogram needs zeroing
    hipMemsetAsync(deg, 0, N_NODES * sizeof(int), stream);

    proj_kernel<<<N_NODES, 64, 0, stream>>>(
        feat, W_in, b_in, W_q, b_q, W_k, b_k, W_v, b_v, Q, Kf0, V0);

    hist_kernel<<<(N_EDGES + 255) / 256, 256, 0, stream>>>(ecol, deg);
    scan_kernel<<<1, SCAN_T, 0, stream>>>(deg, rowptr, cursor);
    scatter_kernel<<<(N_EDGES + 255) / 256, 256, 0, stream>>>(erow, ecol, cursor, csr_src);

    hop1_gather<<<(N_NODES + 3) / 4, 256, 0, stream>>>(
        csr_src, rowptr, deg, Q, Kf0, V0, Kf1, M1, H1, Cd1);

    hop2_gather<<<(N_NODES + 3) / 4, 256, 0, stream>>>(
        csr_src, rowptr, deg, Q, Kf1, M1, H2, Cd2);

    combine_kernel<<<(N_NODES + 255) / 256, 256, 0, stream>>>(
        V0, H1, Cd1, H2, Cd2, hopwise, headwise, W_out, b_out, out);
}

// Round 3
// 507.386 us; speedup vs baseline: 18.3910x; 1.6185x over previous
//
#include <hip/hip_runtime.h>

#define N_NODES 50000
#define N_EDGES 400000
#define F_IN    128
#define HID     64
#define HEADS   4
#define HEADC   16
#define C_CLS   10
#define HC      (HEADS * C_CLS)   // 40
#define M_DIM   (HID * C_CLS)     // 640
#define CST     1e-5f
#define SCAN_T  1024
#define SCAN_PER ((N_NODES + SCAN_T - 1) / SCAN_T)   // 49

#define PTILE 64    // nodes per proj block
#define SFS   132   // feat tile LDS stride (floats): 16B-aligned, (node+k4)%8 superbanks
#define SXS   68    // x tile LDS stride

// -------------------- projections: x -> Q, Kf0, V0 (tiled LDS GEMV) --------------------
__global__ __launch_bounds__(256) void proj_kernel(
    const float* __restrict__ feat,
    const float* __restrict__ W_in, const float* __restrict__ b_in,
    const float* __restrict__ W_q,  const float* __restrict__ b_q,
    const float* __restrict__ W_k,  const float* __restrict__ b_k,
    const float* __restrict__ W_v,  const float* __restrict__ b_v,
    float* __restrict__ Q, float* __restrict__ Kf0, float* __restrict__ V0)
{
    const int nb = blockIdx.x * PTILE;
    const int t  = threadIdx.x;
    __shared__ float sf[PTILE * SFS];   // 33.8 KB
    __shared__ float sx[PTILE * SXS];   // 17.4 KB

    // ---- stage feat tile, coalesced float4 ----
    #pragma unroll
    for (int it = 0; it < 8; ++it) {
        const int flat = it * 256 + t;       // 0..2047  (64 rows x 32 float4)
        const int node = flat >> 5;
        const int kq   = flat & 31;
        const int gn   = nb + node;
        float4 v = make_float4(0.f, 0.f, 0.f, 0.f);
        if (gn < N_NODES) v = *(const float4*)&feat[(size_t)gn * F_IN + kq * 4];
        *(float4*)&sf[node * SFS + kq * 4] = v;
    }
    __syncthreads();

    const int node = t & 63;
    const int og   = __builtin_amdgcn_readfirstlane(t >> 6);   // wave-uniform
    const int gn   = nb + node;

    // ---- phase 1: x = relu(feat @ W_in^T + b_in); this thread owns outs og*16..+15 ----
    float acc[16];
    #pragma unroll
    for (int o = 0; o < 16; ++o) acc[o] = b_in[og * 16 + o];
    for (int k4 = 0; k4 < F_IN / 4; ++k4) {
        const float4 f = *(const float4*)&sf[node * SFS + k4 * 4];
        #pragma unroll
        for (int o = 0; o < 16; ++o) {
            const float4 w = *(const float4*)&W_in[(size_t)(og * 16 + o) * F_IN + k4 * 4];
            acc[o] += f.x * w.x + f.y * w.y + f.z * w.z + f.w * w.w;
        }
    }
    #pragma unroll
    for (int o4 = 0; o4 < 4; ++o4) {
        float4 xo = make_float4(fmaxf(acc[o4 * 4 + 0], 0.f), fmaxf(acc[o4 * 4 + 1], 0.f),
                                fmaxf(acc[o4 * 4 + 2], 0.f), fmaxf(acc[o4 * 4 + 3], 0.f));
        *(float4*)&sx[node * SXS + og * 16 + o4 * 4] = xo;
    }
    __syncthreads();

    // ---- phase 2: Q/K (16 outs each) + V (10 outs) for this node ----
    float aq[16], ak[16], av[10];
    #pragma unroll
    for (int o = 0; o < 16; ++o) { aq[o] = b_q[og * 16 + o]; ak[o] = b_k[og * 16 + o]; }
    #pragma unroll
    for (int j = 0; j < 10; ++j) av[j] = b_v[og * 10 + j];

    for (int k4 = 0; k4 < HID / 4; ++k4) {
        const float4 xv = *(const float4*)&sx[node * SXS + k4 * 4];
        #pragma unroll
        for (int o = 0; o < 16; ++o) {
            const float4 wq = *(const float4*)&W_q[(size_t)(og * 16 + o) * HID + k4 * 4];
            aq[o] += xv.x * wq.x + xv.y * wq.y + xv.z * wq.z + xv.w * wq.w;
            const float4 wk = *(const float4*)&W_k[(size_t)(og * 16 + o) * HID + k4 * 4];
            ak[o] += xv.x * wk.x + xv.y * wk.y + xv.z * wk.z + xv.w * wk.w;
        }
        #pragma unroll
        for (int j = 0; j < 10; ++j) {
            const float4 wv = *(const float4*)&W_v[(size_t)(og * 10 + j) * HID + k4 * 4];
            av[j] += xv.x * wv.x + xv.y * wv.y + xv.z * wv.z + xv.w * wv.w;
        }
    }

    if (gn < N_NODES) {
        #pragma unroll
        for (int o = 0; o < 16; ++o) {
            const float zq = aq[o];
            Q  [(size_t)gn * HID + og * 16 + o] = (zq > 0.f) ? (zq + 1.f) : expf(zq);
            const float zk = ak[o];
            Kf0[(size_t)gn * HID + og * 16 + o] = (zk > 0.f) ? (zk + 1.f) : expf(zk);
        }
        #pragma unroll
        for (int j = 0; j < 10; ++j)
            V0[(size_t)gn * HC + og * 10 + j] = av[j];
    }
}

// -------------------- CSR build --------------------
__global__ __launch_bounds__(256) void hist_kernel(
    const int* __restrict__ ecol, int* __restrict__ deg)
{
    const int e = blockIdx.x * 256 + threadIdx.x;
    if (e < N_EDGES) atomicAdd(&deg[ecol[e]], 1);
}

__global__ __launch_bounds__(SCAN_T) void scan_kernel(
    const int* __restrict__ deg, int* __restrict__ rowptr, int* __restrict__ cursor)
{
    __shared__ int part[SCAN_T];
    const int t = threadIdx.x;
    const int base = t * SCAN_PER;
    int s = 0;
    for (int i = 0; i < SCAN_PER; ++i) {
        int idx = base + i;
        if (idx < N_NODES) s += deg[idx];
    }
    part[t] = s;
    __syncthreads();
    for (int off = 1; off < SCAN_T; off <<= 1) {
        int v = (t >= off) ? part[t - off] : 0;
        __syncthreads();
        part[t] += v;
        __syncthreads();
    }
    int run = (t == 0) ? 0 : part[t - 1];
    for (int i = 0; i < SCAN_PER; ++i) {
        int idx = base + i;
        if (idx < N_NODES) {
            rowptr[idx] = run;
            cursor[idx] = run;
            run += deg[idx];
        }
    }
}

__global__ __launch_bounds__(256) void scatter_kernel(
    const int* __restrict__ erow, const int* __restrict__ ecol,
    int* __restrict__ cursor, int* __restrict__ csr_src)
{
    const int e = blockIdx.x * 256 + threadIdx.x;
    if (e < N_EDGES) {
        const int pos = atomicAdd(&cursor[ecol[e]], 1);
        csr_src[pos] = erow[e];
    }
}

// -------------------- hop 1: gather, no atomics --------------------
__global__ __launch_bounds__(256) void hop1_gather(
    const int* __restrict__ csr_src, const int* __restrict__ rowptr,
    const int* __restrict__ deg,
    const float* __restrict__ Q, const float* __restrict__ Kf0,
    const float* __restrict__ V0,
    float* __restrict__ Kf1, float* __restrict__ M1,
    float* __restrict__ H1, float* __restrict__ Cd1)
{
    const int sub  = threadIdx.x >> 6;
    const int lane = threadIdx.x & 63;
    const int n    = blockIdx.x * 4 + sub;
    if (n >= N_NODES) return;
    const int h = lane >> 4;
    const int r = lane & 15;

    const float q = Q[(size_t)n * HID + lane];
    float accM[C_CLS];
    #pragma unroll
    for (int j = 0; j < C_CLS; ++j) accM[j] = 0.0f;
    float accK = 0.0f, accH = 0.0f, accA = 0.0f;

    const int beg = rowptr[n];
    const int d   = deg[n];
    for (int e = 0; e < d; ++e) {
        const int s = csr_src[beg + e];
        const float kf = Kf0[(size_t)s * HID + lane];
        accK += kf;
        float p = q * kf;
        p += __shfl_xor(p, 1);
        p += __shfl_xor(p, 2);
        p += __shfl_xor(p, 4);
        p += __shfl_xor(p, 8);
        accA += p;
        const float* v = V0 + (size_t)s * HC + h * C_CLS;
        #pragma unroll
        for (int j = 0; j < C_CLS; ++j) {
            const float vj = v[j];
            accM[j] += kf * vj;
            accH = (j == r) ? (accH + p * vj) : accH;
        }
    }

    Kf1[(size_t)n * HID + lane] = accK;
    float* m = M1 + (size_t)n * M_DIM;
    #pragma unroll
    for (int j = 0; j < C_CLS; ++j) m[j * HID + lane] = accM[j];
    if (r == 0)     Cd1[(size_t)n * HEADS + h] = accA;
    if (r < C_CLS)  H1 [(size_t)n * HC + h * C_CLS + r] = accH;
}

// -------------------- hop 2: gather; M2/Kf2 summed in registers --------------------
__global__ __launch_bounds__(256) void hop2_gather(
    const int* __restrict__ csr_src, const int* __restrict__ rowptr,
    const int* __restrict__ deg,
    const float* __restrict__ Q, const float* __restrict__ Kf1,
    const float* __restrict__ M1,
    float* __restrict__ H2, float* __restrict__ Cd2)
{
    const int sub  = threadIdx.x >> 6;
    const int lane = threadIdx.x & 63;
    const int n    = blockIdx.x * 4 + sub;
    if (n >= N_NODES) return;
    const int h = lane >> 4;
    const int r = lane & 15;

    const float q = Q[(size_t)n * HID + lane];
    float accM[C_CLS];
    #pragma unroll
    for (int j = 0; j < C_CLS; ++j) accM[j] = 0.0f;
    float accK = 0.0f;

    const int beg = rowptr[n];
    const int d   = deg[n];
    for (int e = 0; e < d; ++e) {
        const int s = csr_src[beg + e];
        accK += Kf1[(size_t)s * HID + lane];
        const float* m = M1 + (size_t)s * M_DIM;
        #pragma unroll
        for (int j = 0; j < C_CLS; ++j) accM[j] += m[j * HID + lane];
    }

    float pc = q * accK;
    pc += __shfl_xor(pc, 1);
    pc += __shfl_xor(pc, 2);
    pc += __shfl_xor(pc, 4);
    pc += __shfl_xor(pc, 8);
    if (r == 0) Cd2[(size_t)n * HEADS + h] = pc;

    float pj[C_CLS];
    #pragma unroll
    for (int j = 0; j < C_CLS; ++j) {
        pj[j] = q * accM[j];
        pj[j] += __shfl_xor(pj[j], 1);
        pj[j] += __shfl_xor(pj[j], 2);
        pj[j] += __shfl_xor(pj[j], 4);
        pj[j] += __shfl_xor(pj[j], 8);
    }
    if (r < C_CLS) {
        float val = 0.0f;
        #pragma unroll
        for (int j = 0; j < C_CLS; ++j) val = (r == j) ? pj[j] : val;
        H2[(size_t)n * HC + h * C_CLS + r] = val;
    }
}

// -------------------- combine + output projection --------------------
__global__ __launch_bounds__(256) void combine_kernel(
    const float* __restrict__ V0,
    const float* __restrict__ H1, const float* __restrict__ Cd1,
    const float* __restrict__ H2, const float* __restrict__ Cd2,
    const float* __restrict__ hopwise, const float* __restrict__ headwise,
    const float* __restrict__ W_out, const float* __restrict__ b_out,
    float* __restrict__ out)
{
    const int n = blockIdx.x * blockDim.x + threadIdx.x;
    if (n >= N_NODES) return;

    float hv[HEADS][2];
    float m0 = -1e30f, m1 = -1e30f;
    #pragma unroll
    for (int h = 0; h < HEADS; ++h) {
        hv[h][0] = headwise[h * 2 + 0];
        hv[h][1] = headwise[h * 2 + 1];
        m0 = fmaxf(m0, hv[h][0]);
        m1 = fmaxf(m1, hv[h][1]);
    }
    float s0 = 0.0f, s1 = 0.0f;
    float e0[HEADS], e1[HEADS];
    #pragma unroll
    for (int h = 0; h < HEADS; ++h) {
        e0[h] = expf(hv[h][0] - m0); s0 += e0[h];
        e1[h] = expf(hv[h][1] - m1); s1 += e1[h];
    }
    const float hw0 = hopwise[0];
    float g1[HEADS], g2[HEADS];
    #pragma unroll
    for (int h = 0; h < HEADS; ++h) {
        g1[h] = hopwise[1] * e0[h] / s0;
        g2[h] = hopwise[2] * e1[h] / s1;
    }

    float hidden[HC];
    #pragma unroll
    for (int h = 0; h < HEADS; ++h) {
        const float icd1 = 1.0f / (Cd1[(size_t)n * HEADS + h] + CST);
        const float icd2 = 1.0f / (Cd2[(size_t)n * HEADS + h] + CST);
        #pragma unroll
        for (int j = 0; j < C_CLS; ++j) {
            const int idx = h * C_CLS + j;
            hidden[idx] = hw0 * V0[(size_t)n * HC + idx]
                        + g1[h] * H1[(size_t)n * HC + idx] * icd1
                        + g2[h] * H2[(size_t)n * HC + idx] * icd2;
        }
    }

    #pragma unroll
    for (int c = 0; c < C_CLS; ++c) {
        float acc = b_out[c];
        const float* w = W_out + c * HC;
        #pragma unroll
        for (int k = 0; k < HC; ++k) acc += w[k] * hidden[k];
        out[(size_t)n * C_CLS + c] = acc;
    }
}

// -------------------- launch --------------------
extern "C" void kernel_launch(void* const* d_in, const int* in_sizes, int n_in,
                              void* d_out, int out_size, void* d_ws, size_t ws_size,
                              hipStream_t stream)
{
    const float* feat     = (const float*)d_in[0];
    const int*   eidx     = (const int*)  d_in[1];
    const float* W_in     = (const float*)d_in[2];
    const float* b_in     = (const float*)d_in[3];
    const float* W_q      = (const float*)d_in[4];
    const float* b_q      = (const float*)d_in[5];
    const float* W_k      = (const float*)d_in[6];
    const float* b_k      = (const float*)d_in[7];
    const float* W_v      = (const float*)d_in[8];
    const float* b_v      = (const float*)d_in[9];
    const float* W_out    = (const float*)d_in[10];
    const float* b_out    = (const float*)d_in[11];
    const float* hopwise  = (const float*)d_in[12];
    const float* headwise = (const float*)d_in[13];
    float* out = (float*)d_out;

    const int* erow = eidx;
    const int* ecol = eidx + N_EDGES;

    float* ws = (float*)d_ws;
    size_t off = 0;
    float* Q    = ws + off; off += (size_t)N_NODES * HID;
    float* Kf0  = ws + off; off += (size_t)N_NODES * HID;
    float* V0   = ws + off; off += (size_t)N_NODES * HC;
    float* Kf1  = ws + off; off += (size_t)N_NODES * HID;
    float* M1   = ws + off; off += (size_t)N_NODES * M_DIM;
    float* H1   = ws + off; off += (size_t)N_NODES * HC;
    float* Cd1  = ws + off; off += (size_t)N_NODES * HEADS;
    float* H2   = ws + off; off += (size_t)N_NODES * HC;
    float* Cd2  = ws + off; off += (size_t)N_NODES * HEADS;
    int* iws = (int*)(ws + off);
    int* deg     = iws;
    int* rowptr  = iws + N_NODES;
    int* cursor  = iws + 2 * N_NODES;
    int* csr_src = iws + 3 * N_NODES;

    hipMemsetAsync(deg, 0, N_NODES * sizeof(int), stream);

    proj_kernel<<<(N_NODES + PTILE - 1) / PTILE, 256, 0, stream>>>(
        feat, W_in, b_in, W_q, b_q, W_k, b_k, W_v, b_v, Q, Kf0, V0);

    hist_kernel<<<(N_EDGES + 255) / 256, 256, 0, stream>>>(ecol, deg);
    scan_kernel<<<1, SCAN_T, 0, stream>>>(deg, rowptr, cursor);
    scatter_kernel<<<(N_EDGES + 255) / 256, 256, 0, stream>>>(erow, ecol, cursor, csr_src);

    hop1_gather<<<(N_NODES + 3) / 4, 256, 0, stream>>>(
        csr_src, rowptr, deg, Q, Kf0, V0, Kf1, M1, H1, Cd1);

    hop2_gather<<<(N_NODES + 3) / 4, 256, 0, stream>>>(
        csr_src, rowptr, deg, Q, Kf1, M1, H2, Cd2);

    combine_kernel<<<(N_NODES + 255) / 256, 256, 0, stream>>>(
        V0, H1, Cd1, H2, Cd2, hopwise, headwise, W_out, b_out, out);
}

// Round 4
// 428.401 us; speedup vs baseline: 21.7817x; 1.1844x over previous
//
#include <hip/hip_runtime.h>
#include <hip/hip_bf16.h>

#define N_NODES 50000
#define N_EDGES 400000
#define F_IN    128
#define HID     64
#define HEADS   4
#define HEADC   16
#define C_CLS   10
#define HC      (HEADS * C_CLS)   // 40
#define M_DW    (HID * C_CLS / 2) // 320 dwords (bf16x2) per node
#define CST     1e-5f
#define SCAN_T  1024
#define SCAN_PER ((N_NODES + SCAN_T - 1) / SCAN_T)   // 49

#define PTILE 64    // nodes per proj block
#define SFS   132   // feat tile LDS stride (floats)
#define SXS   68    // x tile LDS stride

__device__ __forceinline__ unsigned pack_bf16x2(float a, float b) {
    union { __hip_bfloat162 h2; unsigned u; } cv;
    cv.h2.x = __float2bfloat16(a);
    cv.h2.y = __float2bfloat16(b);
    return cv.u;
}
__device__ __forceinline__ void unpack_bf16x2(unsigned w, float& a, float& b) {
    union { unsigned u; __hip_bfloat162 h2; } cv;
    cv.u = w;
    a = __bfloat162float(cv.h2.x);
    b = __bfloat162float(cv.h2.y);
}

// -------------------- projections: x -> Q, Kf0, V0 (tiled LDS GEMV) --------------------
__global__ __launch_bounds__(256) void proj_kernel(
    const float* __restrict__ feat,
    const float* __restrict__ W_in, const float* __restrict__ b_in,
    const float* __restrict__ W_q,  const float* __restrict__ b_q,
    const float* __restrict__ W_k,  const float* __restrict__ b_k,
    const float* __restrict__ W_v,  const float* __restrict__ b_v,
    float* __restrict__ Q, float* __restrict__ Kf0, float* __restrict__ V0)
{
    const int nb = blockIdx.x * PTILE;
    const int t  = threadIdx.x;
    __shared__ float sf[PTILE * SFS];
    __shared__ float sx[PTILE * SXS];

    #pragma unroll
    for (int it = 0; it < 8; ++it) {
        const int flat = it * 256 + t;
        const int node = flat >> 5;
        const int kq   = flat & 31;
        const int gn   = nb + node;
        float4 v = make_float4(0.f, 0.f, 0.f, 0.f);
        if (gn < N_NODES) v = *(const float4*)&feat[(size_t)gn * F_IN + kq * 4];
        *(float4*)&sf[node * SFS + kq * 4] = v;
    }
    __syncthreads();

    const int node = t & 63;
    const int og   = __builtin_amdgcn_readfirstlane(t >> 6);
    const int gn   = nb + node;

    float acc[16];
    #pragma unroll
    for (int o = 0; o < 16; ++o) acc[o] = b_in[og * 16 + o];
    for (int k4 = 0; k4 < F_IN / 4; ++k4) {
        const float4 f = *(const float4*)&sf[node * SFS + k4 * 4];
        #pragma unroll
        for (int o = 0; o < 16; ++o) {
            const float4 w = *(const float4*)&W_in[(size_t)(og * 16 + o) * F_IN + k4 * 4];
            acc[o] += f.x * w.x + f.y * w.y + f.z * w.z + f.w * w.w;
        }
    }
    #pragma unroll
    for (int o4 = 0; o4 < 4; ++o4) {
        float4 xo = make_float4(fmaxf(acc[o4 * 4 + 0], 0.f), fmaxf(acc[o4 * 4 + 1], 0.f),
                                fmaxf(acc[o4 * 4 + 2], 0.f), fmaxf(acc[o4 * 4 + 3], 0.f));
        *(float4*)&sx[node * SXS + og * 16 + o4 * 4] = xo;
    }
    __syncthreads();

    float aq[16], ak[16], av[10];
    #pragma unroll
    for (int o = 0; o < 16; ++o) { aq[o] = b_q[og * 16 + o]; ak[o] = b_k[og * 16 + o]; }
    #pragma unroll
    for (int j = 0; j < 10; ++j) av[j] = b_v[og * 10 + j];

    for (int k4 = 0; k4 < HID / 4; ++k4) {
        const float4 xv = *(const float4*)&sx[node * SXS + k4 * 4];
        #pragma unroll
        for (int o = 0; o < 16; ++o) {
            const float4 wq = *(const float4*)&W_q[(size_t)(og * 16 + o) * HID + k4 * 4];
            aq[o] += xv.x * wq.x + xv.y * wq.y + xv.z * wq.z + xv.w * wq.w;
            const float4 wk = *(const float4*)&W_k[(size_t)(og * 16 + o) * HID + k4 * 4];
            ak[o] += xv.x * wk.x + xv.y * wk.y + xv.z * wk.z + xv.w * wk.w;
        }
        #pragma unroll
        for (int j = 0; j < 10; ++j) {
            const float4 wv = *(const float4*)&W_v[(size_t)(og * 10 + j) * HID + k4 * 4];
            av[j] += xv.x * wv.x + xv.y * wv.y + xv.z * wv.z + xv.w * wv.w;
        }
    }

    if (gn < N_NODES) {
        #pragma unroll
        for (int o = 0; o < 16; ++o) {
            const float zq = aq[o];
            Q  [(size_t)gn * HID + og * 16 + o] = (zq > 0.f) ? (zq + 1.f) : expf(zq);
            const float zk = ak[o];
            Kf0[(size_t)gn * HID + og * 16 + o] = (zk > 0.f) ? (zk + 1.f) : expf(zk);
        }
        #pragma unroll
        for (int j = 0; j < 10; ++j)
            V0[(size_t)gn * HC + og * 10 + j] = av[j];
    }
}

// -------------------- CSR build --------------------
__global__ __launch_bounds__(256) void hist_kernel(
    const int* __restrict__ ecol, int* __restrict__ deg)
{
    const int e = blockIdx.x * 256 + threadIdx.x;
    if (e < N_EDGES) atomicAdd(&deg[ecol[e]], 1);
}

__global__ __launch_bounds__(SCAN_T) void scan_kernel(
    const int* __restrict__ deg, int* __restrict__ rowptr, int* __restrict__ cursor)
{
    __shared__ int part[SCAN_T];
    const int t = threadIdx.x;
    const int base = t * SCAN_PER;
    int s = 0;
    for (int i = 0; i < SCAN_PER; ++i) {
        int idx = base + i;
        if (idx < N_NODES) s += deg[idx];
    }
    part[t] = s;
    __syncthreads();
    for (int off = 1; off < SCAN_T; off <<= 1) {
        int v = (t >= off) ? part[t - off] : 0;
        __syncthreads();
        part[t] += v;
        __syncthreads();
    }
    int run = (t == 0) ? 0 : part[t - 1];
    for (int i = 0; i < SCAN_PER; ++i) {
        int idx = base + i;
        if (idx < N_NODES) {
            rowptr[idx] = run;
            cursor[idx] = run;
            run += deg[idx];
        }
    }
}

__global__ __launch_bounds__(256) void scatter_kernel(
    const int* __restrict__ erow, const int* __restrict__ ecol,
    int* __restrict__ cursor, int* __restrict__ csr_src)
{
    const int e = blockIdx.x * 256 + threadIdx.x;
    if (e < N_EDGES) {
        const int pos = atomicAdd(&cursor[ecol[e]], 1);
        csr_src[pos] = erow[e];
    }
}

// -------------------- hop 1: gather; M1/Kf1 stored bf16 --------------------
__global__ __launch_bounds__(256) void hop1_gather(
    const int* __restrict__ csr_src, const int* __restrict__ rowptr,
    const int* __restrict__ deg,
    const float* __restrict__ Q, const float* __restrict__ Kf0,
    const float* __restrict__ V0,
    __hip_bfloat16* __restrict__ Kf1, unsigned* __restrict__ M1,
    float* __restrict__ H1, float* __restrict__ Cd1)
{
    const int sub  = threadIdx.x >> 6;
    const int lane = threadIdx.x & 63;
    const int n    = blockIdx.x * 4 + sub;
    if (n >= N_NODES) return;
    const int h = lane >> 4;
    const int r = lane & 15;

    const float q = Q[(size_t)n * HID + lane];
    float accM[C_CLS];
    #pragma unroll
    for (int j = 0; j < C_CLS; ++j) accM[j] = 0.0f;
    float accK = 0.0f, accH = 0.0f, accA = 0.0f;

    const int beg = rowptr[n];
    const int d   = deg[n];
    for (int e = 0; e < d; ++e) {
        const int s = csr_src[beg + e];
        const float kf = Kf0[(size_t)s * HID + lane];
        accK += kf;
        float p = q * kf;
        p += __shfl_xor(p, 1);
        p += __shfl_xor(p, 2);
        p += __shfl_xor(p, 4);
        p += __shfl_xor(p, 8);
        accA += p;
        const float* v = V0 + (size_t)s * HC + h * C_CLS;
        #pragma unroll
        for (int j = 0; j < C_CLS; ++j) {
            const float vj = v[j];
            accM[j] += kf * vj;
            accH = (j == r) ? (accH + p * vj) : accH;
        }
    }

    Kf1[(size_t)n * HID + lane] = __float2bfloat16(accK);
    unsigned* m = M1 + (size_t)n * M_DW;
    #pragma unroll
    for (int j2 = 0; j2 < C_CLS / 2; ++j2)
        m[j2 * HID + lane] = pack_bf16x2(accM[2 * j2], accM[2 * j2 + 1]);  // coalesced
    if (r == 0)     Cd1[(size_t)n * HEADS + h] = accA;
    if (r < C_CLS)  H1 [(size_t)n * HC + h * C_CLS + r] = accH;
}

// -------------------- hop 2: gather; M2/Kf2 summed in registers --------------------
__global__ __launch_bounds__(256) void hop2_gather(
    const int* __restrict__ csr_src, const int* __restrict__ rowptr,
    const int* __restrict__ deg,
    const float* __restrict__ Q, const __hip_bfloat16* __restrict__ Kf1,
    const unsigned* __restrict__ M1,
    float* __restrict__ H2, float* __restrict__ Cd2)
{
    const int sub  = threadIdx.x >> 6;
    const int lane = threadIdx.x & 63;
    const int n    = blockIdx.x * 4 + sub;
    if (n >= N_NODES) return;
    const int h = lane >> 4;
    const int r = lane & 15;

    const float q = Q[(size_t)n * HID + lane];
    float accM[C_CLS];
    #pragma unroll
    for (int j = 0; j < C_CLS; ++j) accM[j] = 0.0f;
    float accK = 0.0f;

    const int beg = rowptr[n];
    const int d   = deg[n];
    for (int e = 0; e < d; ++e) {
        const int s = csr_src[beg + e];
        accK += __bfloat162float(Kf1[(size_t)s * HID + lane]);
        const unsigned* m = M1 + (size_t)s * M_DW;
        #pragma unroll
        for (int j2 = 0; j2 < C_CLS / 2; ++j2) {
            float a, b;
            unpack_bf16x2(m[j2 * HID + lane], a, b);   // coalesced 256B/wave
            accM[2 * j2]     += a;
            accM[2 * j2 + 1] += b;
        }
    }

    float pc = q * accK;
    pc += __shfl_xor(pc, 1);
    pc += __shfl_xor(pc, 2);
    pc += __shfl_xor(pc, 4);
    pc += __shfl_xor(pc, 8);
    if (r == 0) Cd2[(size_t)n * HEADS + h] = pc;

    float pj[C_CLS];
    #pragma unroll
    for (int j = 0; j < C_CLS; ++j) {
        pj[j] = q * accM[j];
        pj[j] += __shfl_xor(pj[j], 1);
        pj[j] += __shfl_xor(pj[j], 2);
        pj[j] += __shfl_xor(pj[j], 4);
        pj[j] += __shfl_xor(pj[j], 8);
    }
    if (r < C_CLS) {
        float val = 0.0f;
        #pragma unroll
        for (int j = 0; j < C_CLS; ++j) val = (r == j) ? pj[j] : val;
        H2[(size_t)n * HC + h * C_CLS + r] = val;
    }
}

// -------------------- combine + output projection --------------------
__global__ __launch_bounds__(256) void combine_kernel(
    const float* __restrict__ V0,
    const float* __restrict__ H1, const float* __restrict__ Cd1,
    const float* __restrict__ H2, const float* __restrict__ Cd2,
    const float* __restrict__ hopwise, const float* __restrict__ headwise,
    const float* __restrict__ W_out, const float* __restrict__ b_out,
    float* __restrict__ out)
{
    const int n = blockIdx.x * blockDim.x + threadIdx.x;
    if (n >= N_NODES) return;

    float hv[HEADS][2];
    float m0 = -1e30f, m1 = -1e30f;
    #pragma unroll
    for (int h = 0; h < HEADS; ++h) {
        hv[h][0] = headwise[h * 2 + 0];
        hv[h][1] = headwise[h * 2 + 1];
        m0 = fmaxf(m0, hv[h][0]);
        m1 = fmaxf(m1, hv[h][1]);
    }
    float s0 = 0.0f, s1 = 0.0f;
    float e0[HEADS], e1[HEADS];
    #pragma unroll
    for (int h = 0; h < HEADS; ++h) {
        e0[h] = expf(hv[h][0] - m0); s0 += e0[h];
        e1[h] = expf(hv[h][1] - m1); s1 += e1[h];
    }
    const float hw0 = hopwise[0];
    float g1[HEADS], g2[HEADS];
    #pragma unroll
    for (int h = 0; h < HEADS; ++h) {
        g1[h] = hopwise[1] * e0[h] / s0;
        g2[h] = hopwise[2] * e1[h] / s1;
    }

    float hidden[HC];
    #pragma unroll
    for (int h = 0; h < HEADS; ++h) {
        const float icd1 = 1.0f / (Cd1[(size_t)n * HEADS + h] + CST);
        const float icd2 = 1.0f / (Cd2[(size_t)n * HEADS + h] + CST);
        #pragma unroll
        for (int j = 0; j < C_CLS; ++j) {
            const int idx = h * C_CLS + j;
            hidden[idx] = hw0 * V0[(size_t)n * HC + idx]
                        + g1[h] * H1[(size_t)n * HC + idx] * icd1
                        + g2[h] * H2[(size_t)n * HC + idx] * icd2;
        }
    }

    #pragma unroll
    for (int c = 0; c < C_CLS; ++c) {
        float acc = b_out[c];
        const float* w = W_out + c * HC;
        #pragma unroll
        for (int k = 0; k < HC; ++k) acc += w[k] * hidden[k];
        out[(size_t)n * C_CLS + c] = acc;
    }
}

// -------------------- launch --------------------
extern "C" void kernel_launch(void* const* d_in, const int* in_sizes, int n_in,
                              void* d_out, int out_size, void* d_ws, size_t ws_size,
                              hipStream_t stream)
{
    const float* feat     = (const float*)d_in[0];
    const int*   eidx     = (const int*)  d_in[1];
    const float* W_in     = (const float*)d_in[2];
    const float* b_in     = (const float*)d_in[3];
    const float* W_q      = (const float*)d_in[4];
    const float* b_q      = (const float*)d_in[5];
    const float* W_k      = (const float*)d_in[6];
    const float* b_k      = (const float*)d_in[7];
    const float* W_v      = (const float*)d_in[8];
    const float* b_v      = (const float*)d_in[9];
    const float* W_out    = (const float*)d_in[10];
    const float* b_out    = (const float*)d_in[11];
    const float* hopwise  = (const float*)d_in[12];
    const float* headwise = (const float*)d_in[13];
    float* out = (float*)d_out;

    const int* erow = eidx;
    const int* ecol = eidx + N_EDGES;

    float* ws = (float*)d_ws;
    size_t off = 0;
    float* Q    = ws + off; off += (size_t)N_NODES * HID;
    float* Kf0  = ws + off; off += (size_t)N_NODES * HID;
    float* V0   = ws + off; off += (size_t)N_NODES * HC;
    __hip_bfloat16* Kf1 = (__hip_bfloat16*)(ws + off); off += (size_t)N_NODES * HID / 2;
    unsigned* M1 = (unsigned*)(ws + off); off += (size_t)N_NODES * M_DW;
    float* H1   = ws + off; off += (size_t)N_NODES * HC;
    float* Cd1  = ws + off; off += (size_t)N_NODES * HEADS;
    float* H2   = ws + off; off += (size_t)N_NODES * HC;
    float* Cd2  = ws + off; off += (size_t)N_NODES * HEADS;
    int* iws = (int*)(ws + off);
    int* deg     = iws;
    int* rowptr  = iws + N_NODES;
    int* cursor  = iws + 2 * N_NODES;
    int* csr_src = iws + 3 * N_NODES;

    hipMemsetAsync(deg, 0, N_NODES * sizeof(int), stream);

    proj_kernel<<<(N_NODES + PTILE - 1) / PTILE, 256, 0, stream>>>(
        feat, W_in, b_in, W_q, b_q, W_k, b_k, W_v, b_v, Q, Kf0, V0);

    hist_kernel<<<(N_EDGES + 255) / 256, 256, 0, stream>>>(ecol, deg);
    scan_kernel<<<1, SCAN_T, 0, stream>>>(deg, rowptr, cursor);
    scatter_kernel<<<(N_EDGES + 255) / 256, 256, 0, stream>>>(erow, ecol, cursor, csr_src);

    hop1_gather<<<(N_NODES + 3) / 4, 256, 0, stream>>>(
        csr_src, rowptr, deg, Q, Kf0, V0, Kf1, M1, H1, Cd1);

    hop2_gather<<<(N_NODES + 3) / 4, 256, 0, stream>>>(
        csr_src, rowptr, deg, Q, Kf1, M1, H2, Cd2);

    combine_kernel<<<(N_NODES + 255) / 256, 256, 0, stream>>>(
        V0, H1, Cd1, H2, Cd2, hopwise, headwise, W_out, b_out, out);
}

// Round 5
// 311.683 us; speedup vs baseline: 29.9385x; 1.3745x over previous
//
#include <hip/hip_runtime.h>
#include <hip/hip_bf16.h>

#define N_NODES 50000
#define N_EDGES 400000
#define F_IN    128
#define HID     64
#define HEADS   4
#define HEADC   16
#define C_CLS   10
#define HC      (HEADS * C_CLS)   // 40
#define M_DW    (HID * C_CLS / 2) // 320 dwords (bf16x2) per node
#define CST     1e-5f

#define PTILE 64    // nodes per proj block
#define SFS   132   // feat tile LDS stride (floats)
#define SXS   68    // x tile LDS stride

__device__ __forceinline__ unsigned pack_bf16x2(float a, float b) {
    union { __hip_bfloat162 h2; unsigned u; } cv;
    cv.h2.x = __float2bfloat16(a);
    cv.h2.y = __float2bfloat16(b);
    return cv.u;
}
__device__ __forceinline__ void unpack_bf16x2(unsigned w, float& a, float& b) {
    union { unsigned u; __hip_bfloat162 h2; } cv;
    cv.u = w;
    a = __bfloat162float(cv.h2.x);
    b = __bfloat162float(cv.h2.y);
}

// -------------------- projections: x -> Q, Kf0, V0 (tiled LDS GEMV) --------------------
__global__ __launch_bounds__(256) void proj_kernel(
    const float* __restrict__ feat,
    const float* __restrict__ W_in, const float* __restrict__ b_in,
    const float* __restrict__ W_q,  const float* __restrict__ b_q,
    const float* __restrict__ W_k,  const float* __restrict__ b_k,
    const float* __restrict__ W_v,  const float* __restrict__ b_v,
    float* __restrict__ Q, float* __restrict__ Kf0, float* __restrict__ V0)
{
    const int nb = blockIdx.x * PTILE;
    const int t  = threadIdx.x;
    __shared__ float sf[PTILE * SFS];
    __shared__ float sx[PTILE * SXS];

    #pragma unroll
    for (int it = 0; it < 8; ++it) {
        const int flat = it * 256 + t;
        const int node = flat >> 5;
        const int kq   = flat & 31;
        const int gn   = nb + node;
        float4 v = make_float4(0.f, 0.f, 0.f, 0.f);
        if (gn < N_NODES) v = *(const float4*)&feat[(size_t)gn * F_IN + kq * 4];
        *(float4*)&sf[node * SFS + kq * 4] = v;
    }
    __syncthreads();

    const int node = t & 63;
    const int og   = __builtin_amdgcn_readfirstlane(t >> 6);
    const int gn   = nb + node;

    float acc[16];
    #pragma unroll
    for (int o = 0; o < 16; ++o) acc[o] = b_in[og * 16 + o];
    for (int k4 = 0; k4 < F_IN / 4; ++k4) {
        const float4 f = *(const float4*)&sf[node * SFS + k4 * 4];
        #pragma unroll
        for (int o = 0; o < 16; ++o) {
            const float4 w = *(const float4*)&W_in[(size_t)(og * 16 + o) * F_IN + k4 * 4];
            acc[o] += f.x * w.x + f.y * w.y + f.z * w.z + f.w * w.w;
        }
    }
    #pragma unroll
    for (int o4 = 0; o4 < 4; ++o4) {
        float4 xo = make_float4(fmaxf(acc[o4 * 4 + 0], 0.f), fmaxf(acc[o4 * 4 + 1], 0.f),
                                fmaxf(acc[o4 * 4 + 2], 0.f), fmaxf(acc[o4 * 4 + 3], 0.f));
        *(float4*)&sx[node * SXS + og * 16 + o4 * 4] = xo;
    }
    __syncthreads();

    float aq[16], ak[16], av[10];
    #pragma unroll
    for (int o = 0; o < 16; ++o) { aq[o] = b_q[og * 16 + o]; ak[o] = b_k[og * 16 + o]; }
    #pragma unroll
    for (int j = 0; j < 10; ++j) av[j] = b_v[og * 10 + j];

    for (int k4 = 0; k4 < HID / 4; ++k4) {
        const float4 xv = *(const float4*)&sx[node * SXS + k4 * 4];
        #pragma unroll
        for (int o = 0; o < 16; ++o) {
            const float4 wq = *(const float4*)&W_q[(size_t)(og * 16 + o) * HID + k4 * 4];
            aq[o] += xv.x * wq.x + xv.y * wq.y + xv.z * wq.z + xv.w * wq.w;
            const float4 wk = *(const float4*)&W_k[(size_t)(og * 16 + o) * HID + k4 * 4];
            ak[o] += xv.x * wk.x + xv.y * wk.y + xv.z * wk.z + xv.w * wk.w;
        }
        #pragma unroll
        for (int j = 0; j < 10; ++j) {
            const float4 wv = *(const float4*)&W_v[(size_t)(og * 10 + j) * HID + k4 * 4];
            av[j] += xv.x * wv.x + xv.y * wv.y + xv.z * wv.z + xv.w * wv.w;
        }
    }

    if (gn < N_NODES) {
        #pragma unroll
        for (int o = 0; o < 16; ++o) {
            const float zq = aq[o];
            Q  [(size_t)gn * HID + og * 16 + o] = (zq > 0.f) ? (zq + 1.f) : expf(zq);
            const float zk = ak[o];
            Kf0[(size_t)gn * HID + og * 16 + o] = (zk > 0.f) ? (zk + 1.f) : expf(zk);
        }
        #pragma unroll
        for (int j = 0; j < 10; ++j)
            V0[(size_t)gn * HC + og * 10 + j] = av[j];
    }
}

// -------------------- CSR build --------------------
__global__ __launch_bounds__(256) void hist_kernel(
    const int* __restrict__ ecol, int* __restrict__ deg)
{
    const int e = blockIdx.x * 256 + threadIdx.x;
    if (e < N_EDGES) atomicAdd(&deg[ecol[e]], 1);
}

// one-pass segment allocator: block scan + single atomic per block.
// Segment ORDER is arbitrary (each node just gets a private span of size deg[n]).
__global__ __launch_bounds__(256) void offsets_kernel(
    const int* __restrict__ deg, int* __restrict__ rowptr,
    int* __restrict__ cursor, int* __restrict__ gcount)
{
    const int t    = threadIdx.x;
    const int lane = t & 63;
    const int wid  = t >> 6;
    const int n    = blockIdx.x * 256 + t;
    const int d    = (n < N_NODES) ? deg[n] : 0;

    // inclusive scan within wave
    int x = d;
    #pragma unroll
    for (int off = 1; off < 64; off <<= 1) {
        int v = __shfl_up(x, off);
        x += (lane >= off) ? v : 0;
    }

    __shared__ int wsum[4];
    __shared__ int wbase[4];
    __shared__ int bbase;
    if (lane == 63) wsum[wid] = x;
    __syncthreads();
    if (t == 0) {
        int b = 0;
        #pragma unroll
        for (int w = 0; w < 4; ++w) { wbase[w] = b; b += wsum[w]; }
        bbase = atomicAdd(gcount, b);
    }
    __syncthreads();

    if (n < N_NODES) {
        const int excl = bbase + wbase[wid] + (x - d);
        rowptr[n] = excl;
        cursor[n] = excl;
    }
}

__global__ __launch_bounds__(256) void scatter_kernel(
    const int* __restrict__ erow, const int* __restrict__ ecol,
    int* __restrict__ cursor, int* __restrict__ csr_src)
{
    const int e = blockIdx.x * 256 + threadIdx.x;
    if (e < N_EDGES) {
        const int pos = atomicAdd(&cursor[ecol[e]], 1);
        csr_src[pos] = erow[e];
    }
}

// -------------------- hop 1: gather; M1/Kf1 stored bf16 --------------------
__global__ __launch_bounds__(256) void hop1_gather(
    const int* __restrict__ csr_src, const int* __restrict__ rowptr,
    const int* __restrict__ deg,
    const float* __restrict__ Q, const float* __restrict__ Kf0,
    const float* __restrict__ V0,
    __hip_bfloat16* __restrict__ Kf1, unsigned* __restrict__ M1,
    float* __restrict__ H1, float* __restrict__ Cd1)
{
    const int sub  = threadIdx.x >> 6;
    const int lane = threadIdx.x & 63;
    const int n    = blockIdx.x * 4 + sub;
    if (n >= N_NODES) return;
    const int h = lane >> 4;
    const int r = lane & 15;

    const float q = Q[(size_t)n * HID + lane];
    float accM[C_CLS];
    #pragma unroll
    for (int j = 0; j < C_CLS; ++j) accM[j] = 0.0f;
    float accK = 0.0f, accH = 0.0f, accA = 0.0f;

    const int beg = rowptr[n];
    const int d   = deg[n];
    for (int e = 0; e < d; ++e) {
        const int s = csr_src[beg + e];
        const float kf = Kf0[(size_t)s * HID + lane];
        accK += kf;
        float p = q * kf;
        p += __shfl_xor(p, 1);
        p += __shfl_xor(p, 2);
        p += __shfl_xor(p, 4);
        p += __shfl_xor(p, 8);
        accA += p;
        const float* v = V0 + (size_t)s * HC + h * C_CLS;
        #pragma unroll
        for (int j = 0; j < C_CLS; ++j) {
            const float vj = v[j];
            accM[j] += kf * vj;
            accH = (j == r) ? (accH + p * vj) : accH;
        }
    }

    Kf1[(size_t)n * HID + lane] = __float2bfloat16(accK);
    unsigned* m = M1 + (size_t)n * M_DW;
    #pragma unroll
    for (int j2 = 0; j2 < C_CLS / 2; ++j2)
        m[j2 * HID + lane] = pack_bf16x2(accM[2 * j2], accM[2 * j2 + 1]);
    if (r == 0)     Cd1[(size_t)n * HEADS + h] = accA;
    if (r < C_CLS)  H1 [(size_t)n * HC + h * C_CLS + r] = accH;
}

// -------------------- hop 2: gather; M2/Kf2 summed in registers --------------------
__global__ __launch_bounds__(256) void hop2_gather(
    const int* __restrict__ csr_src, const int* __restrict__ rowptr,
    const int* __restrict__ deg,
    const float* __restrict__ Q, const __hip_bfloat16* __restrict__ Kf1,
    const unsigned* __restrict__ M1,
    float* __restrict__ H2, float* __restrict__ Cd2)
{
    const int sub  = threadIdx.x >> 6;
    const int lane = threadIdx.x & 63;
    const int n    = blockIdx.x * 4 + sub;
    if (n >= N_NODES) return;
    const int h = lane >> 4;
    const int r = lane & 15;

    const float q = Q[(size_t)n * HID + lane];
    float accM[C_CLS];
    #pragma unroll
    for (int j = 0; j < C_CLS; ++j) accM[j] = 0.0f;
    float accK = 0.0f;

    const int beg = rowptr[n];
    const int d   = deg[n];
    for (int e = 0; e < d; ++e) {
        const int s = csr_src[beg + e];
        accK += __bfloat162float(Kf1[(size_t)s * HID + lane]);
        const unsigned* m = M1 + (size_t)s * M_DW;
        #pragma unroll
        for (int j2 = 0; j2 < C_CLS / 2; ++j2) {
            float a, b;
            unpack_bf16x2(m[j2 * HID + lane], a, b);
            accM[2 * j2]     += a;
            accM[2 * j2 + 1] += b;
        }
    }

    float pc = q * accK;
    pc += __shfl_xor(pc, 1);
    pc += __shfl_xor(pc, 2);
    pc += __shfl_xor(pc, 4);
    pc += __shfl_xor(pc, 8);
    if (r == 0) Cd2[(size_t)n * HEADS + h] = pc;

    float pj[C_CLS];
    #pragma unroll
    for (int j = 0; j < C_CLS; ++j) {
        pj[j] = q * accM[j];
        pj[j] += __shfl_xor(pj[j], 1);
        pj[j] += __shfl_xor(pj[j], 2);
        pj[j] += __shfl_xor(pj[j], 4);
        pj[j] += __shfl_xor(pj[j], 8);
    }
    if (r < C_CLS) {
        float val = 0.0f;
        #pragma unroll
        for (int j = 0; j < C_CLS; ++j) val = (r == j) ? pj[j] : val;
        H2[(size_t)n * HC + h * C_CLS + r] = val;
    }
}

// -------------------- combine + output projection --------------------
__global__ __launch_bounds__(256) void combine_kernel(
    const float* __restrict__ V0,
    const float* __restrict__ H1, const float* __restrict__ Cd1,
    const float* __restrict__ H2, const float* __restrict__ Cd2,
    const float* __restrict__ hopwise, const float* __restrict__ headwise,
    const float* __restrict__ W_out, const float* __restrict__ b_out,
    float* __restrict__ out)
{
    const int n = blockIdx.x * blockDim.x + threadIdx.x;
    if (n >= N_NODES) return;

    float hv[HEADS][2];
    float m0 = -1e30f, m1 = -1e30f;
    #pragma unroll
    for (int h = 0; h < HEADS; ++h) {
        hv[h][0] = headwise[h * 2 + 0];
        hv[h][1] = headwise[h * 2 + 1];
        m0 = fmaxf(m0, hv[h][0]);
        m1 = fmaxf(m1, hv[h][1]);
    }
    float s0 = 0.0f, s1 = 0.0f;
    float e0[HEADS], e1[HEADS];
    #pragma unroll
    for (int h = 0; h < HEADS; ++h) {
        e0[h] = expf(hv[h][0] - m0); s0 += e0[h];
        e1[h] = expf(hv[h][1] - m1); s1 += e1[h];
    }
    const float hw0 = hopwise[0];
    float g1[HEADS], g2[HEADS];
    #pragma unroll
    for (int h = 0; h < HEADS; ++h) {
        g1[h] = hopwise[1] * e0[h] / s0;
        g2[h] = hopwise[2] * e1[h] / s1;
    }

    float hidden[HC];
    #pragma unroll
    for (int h = 0; h < HEADS; ++h) {
        const float icd1 = 1.0f / (Cd1[(size_t)n * HEADS + h] + CST);
        const float icd2 = 1.0f / (Cd2[(size_t)n * HEADS + h] + CST);
        #pragma unroll
        for (int j = 0; j < C_CLS; ++j) {
            const int idx = h * C_CLS + j;
            hidden[idx] = hw0 * V0[(size_t)n * HC + idx]
                        + g1[h] * H1[(size_t)n * HC + idx] * icd1
                        + g2[h] * H2[(size_t)n * HC + idx] * icd2;
        }
    }

    #pragma unroll
    for (int c = 0; c < C_CLS; ++c) {
        float acc = b_out[c];
        const float* w = W_out + c * HC;
        #pragma unroll
        for (int k = 0; k < HC; ++k) acc += w[k] * hidden[k];
        out[(size_t)n * C_CLS + c] = acc;
    }
}

// -------------------- launch --------------------
extern "C" void kernel_launch(void* const* d_in, const int* in_sizes, int n_in,
                              void* d_out, int out_size, void* d_ws, size_t ws_size,
                              hipStream_t stream)
{
    const float* feat     = (const float*)d_in[0];
    const int*   eidx     = (const int*)  d_in[1];
    const float* W_in     = (const float*)d_in[2];
    const float* b_in     = (const float*)d_in[3];
    const float* W_q      = (const float*)d_in[4];
    const float* b_q      = (const float*)d_in[5];
    const float* W_k      = (const float*)d_in[6];
    const float* b_k      = (const float*)d_in[7];
    const float* W_v      = (const float*)d_in[8];
    const float* b_v      = (const float*)d_in[9];
    const float* W_out    = (const float*)d_in[10];
    const float* b_out    = (const float*)d_in[11];
    const float* hopwise  = (const float*)d_in[12];
    const float* headwise = (const float*)d_in[13];
    float* out = (float*)d_out;

    const int* erow = eidx;
    const int* ecol = eidx + N_EDGES;

    float* ws = (float*)d_ws;
    size_t off = 0;
    float* Q    = ws + off; off += (size_t)N_NODES * HID;
    float* Kf0  = ws + off; off += (size_t)N_NODES * HID;
    float* V0   = ws + off; off += (size_t)N_NODES * HC;
    __hip_bfloat16* Kf1 = (__hip_bfloat16*)(ws + off); off += (size_t)N_NODES * HID / 2;
    unsigned* M1 = (unsigned*)(ws + off); off += (size_t)N_NODES * M_DW;
    float* H1   = ws + off; off += (size_t)N_NODES * HC;
    float* Cd1  = ws + off; off += (size_t)N_NODES * HEADS;
    float* H2   = ws + off; off += (size_t)N_NODES * HC;
    float* Cd2  = ws + off; off += (size_t)N_NODES * HEADS;
    int* iws = (int*)(ws + off);
    int* deg     = iws;                     // N
    int* gcount  = iws + N_NODES;           // 1
    int* rowptr  = iws + N_NODES + 1;       // N
    int* cursor  = iws + 2 * N_NODES + 1;   // N
    int* csr_src = iws + 3 * N_NODES + 1;   // E

    // zero deg histogram + global allocator counter in one memset
    hipMemsetAsync(deg, 0, (N_NODES + 1) * sizeof(int), stream);

    proj_kernel<<<(N_NODES + PTILE - 1) / PTILE, 256, 0, stream>>>(
        feat, W_in, b_in, W_q, b_q, W_k, b_k, W_v, b_v, Q, Kf0, V0);

    hist_kernel<<<(N_EDGES + 255) / 256, 256, 0, stream>>>(ecol, deg);
    offsets_kernel<<<(N_NODES + 255) / 256, 256, 0, stream>>>(deg, rowptr, cursor, gcount);
    scatter_kernel<<<(N_EDGES + 255) / 256, 256, 0, stream>>>(erow, ecol, cursor, csr_src);

    hop1_gather<<<(N_NODES + 3) / 4, 256, 0, stream>>>(
        csr_src, rowptr, deg, Q, Kf0, V0, Kf1, M1, H1, Cd1);

    hop2_gather<<<(N_NODES + 3) / 4, 256, 0, stream>>>(
        csr_src, rowptr, deg, Q, Kf1, M1, H2, Cd2);

    combine_kernel<<<(N_NODES + 255) / 256, 256, 0, stream>>>(
        V0, H1, Cd1, H2, Cd2, hopwise, headwise, W_out, b_out, out);
}

// Round 6
// 279.173 us; speedup vs baseline: 33.4249x; 1.1165x over previous
//
#include <hip/hip_runtime.h>
#include <hip/hip_bf16.h>

#define N_NODES 50000
#define N_EDGES 400000
#define F_IN    128
#define HID     64
#define HEADS   4
#define HEADC   16
#define C_CLS   10
#define HC      (HEADS * C_CLS)   // 40
#define M_DW    (HID * C_CLS / 2) // 320 dwords (bf16x2) per node
#define CST     1e-5f

#define PTILE 64    // nodes per proj block
#define SFS   132   // feat tile LDS stride (floats)
#define SXS   68    // x tile LDS stride

__device__ __forceinline__ unsigned pack_bf16x2(float a, float b) {
    union { __hip_bfloat162 h2; unsigned u; } cv;
    cv.h2.x = __float2bfloat16(a);
    cv.h2.y = __float2bfloat16(b);
    return cv.u;
}
__device__ __forceinline__ void unpack_bf16x2(unsigned w, float& a, float& b) {
    union { unsigned u; __hip_bfloat162 h2; } cv;
    cv.u = w;
    a = __bfloat162float(cv.h2.x);
    b = __bfloat162float(cv.h2.y);
}

// -------------------- projections: 512 threads = 8 waves, 64 nodes/block --------------------
// wave og owns output rows og*8..og*8+7 (Q,K) and og*5..og*5+4 (V); node = lane.
__global__ __launch_bounds__(512) void proj_kernel(
    const float* __restrict__ feat,
    const float* __restrict__ W_in, const float* __restrict__ b_in,
    const float* __restrict__ W_q,  const float* __restrict__ b_q,
    const float* __restrict__ W_k,  const float* __restrict__ b_k,
    const float* __restrict__ W_v,  const float* __restrict__ b_v,
    float* __restrict__ Q, float* __restrict__ Kf0, float* __restrict__ V0)
{
    const int nb = blockIdx.x * PTILE;
    const int t  = threadIdx.x;
    __shared__ float sf[PTILE * SFS];   // 33.8 KB
    __shared__ float sx[PTILE * SXS];   // 17.4 KB

    // ---- stage feat tile: 64 rows x 32 float4 = 2048, 4 per thread ----
    #pragma unroll
    for (int it = 0; it < 4; ++it) {
        const int flat = it * 512 + t;
        const int node = flat >> 5;
        const int kq   = flat & 31;
        const int gn   = nb + node;
        float4 v = make_float4(0.f, 0.f, 0.f, 0.f);
        if (gn < N_NODES) v = *(const float4*)&feat[(size_t)gn * F_IN + kq * 4];
        *(float4*)&sf[node * SFS + kq * 4] = v;
    }
    __syncthreads();

    const int node = t & 63;
    const int og   = __builtin_amdgcn_readfirstlane(t >> 6);   // 0..7, wave-uniform
    const int gn   = nb + node;

    // ---- phase 1: x = relu(feat @ W_in^T + b_in); 8 outs per thread ----
    float acc[8];
    #pragma unroll
    for (int o = 0; o < 8; ++o) acc[o] = b_in[og * 8 + o];
    for (int k4 = 0; k4 < F_IN / 4; ++k4) {
        const float4 f = *(const float4*)&sf[node * SFS + k4 * 4];
        #pragma unroll
        for (int o = 0; o < 8; ++o) {
            const float4 w = *(const float4*)&W_in[(size_t)(og * 8 + o) * F_IN + k4 * 4];
            acc[o] += f.x * w.x + f.y * w.y + f.z * w.z + f.w * w.w;
        }
    }
    #pragma unroll
    for (int o4 = 0; o4 < 2; ++o4) {
        float4 xo = make_float4(fmaxf(acc[o4 * 4 + 0], 0.f), fmaxf(acc[o4 * 4 + 1], 0.f),
                                fmaxf(acc[o4 * 4 + 2], 0.f), fmaxf(acc[o4 * 4 + 3], 0.f));
        *(float4*)&sx[node * SXS + og * 8 + o4 * 4] = xo;
    }
    __syncthreads();

    // ---- phase 2: Q/K (8 outs each) + V (5 outs) ----
    float aq[8], ak[8], av[5];
    #pragma unroll
    for (int o = 0; o < 8; ++o) { aq[o] = b_q[og * 8 + o]; ak[o] = b_k[og * 8 + o]; }
    #pragma unroll
    for (int j = 0; j < 5; ++j) av[j] = b_v[og * 5 + j];

    for (int k4 = 0; k4 < HID / 4; ++k4) {
        const float4 xv = *(const float4*)&sx[node * SXS + k4 * 4];
        #pragma unroll
        for (int o = 0; o < 8; ++o) {
            const float4 wq = *(const float4*)&W_q[(size_t)(og * 8 + o) * HID + k4 * 4];
            aq[o] += xv.x * wq.x + xv.y * wq.y + xv.z * wq.z + xv.w * wq.w;
            const float4 wk = *(const float4*)&W_k[(size_t)(og * 8 + o) * HID + k4 * 4];
            ak[o] += xv.x * wk.x + xv.y * wk.y + xv.z * wk.z + xv.w * wk.w;
        }
        #pragma unroll
        for (int j = 0; j < 5; ++j) {
            const float4 wv = *(const float4*)&W_v[(size_t)(og * 5 + j) * HID + k4 * 4];
            av[j] += xv.x * wv.x + xv.y * wv.y + xv.z * wv.z + xv.w * wv.w;
        }
    }

    if (gn < N_NODES) {
        #pragma unroll
        for (int o = 0; o < 8; ++o) {
            const float zq = aq[o];
            Q  [(size_t)gn * HID + og * 8 + o] = (zq > 0.f) ? (zq + 1.f) : expf(zq);
            const float zk = ak[o];
            Kf0[(size_t)gn * HID + og * 8 + o] = (zk > 0.f) ? (zk + 1.f) : expf(zk);
        }
        #pragma unroll
        for (int j = 0; j < 5; ++j)
            V0[(size_t)gn * HC + og * 5 + j] = av[j];
    }
}

// -------------------- CSR build --------------------
__global__ __launch_bounds__(256) void hist_kernel(
    const int* __restrict__ ecol, int* __restrict__ deg)
{
    const int e = blockIdx.x * 256 + threadIdx.x;
    if (e < N_EDGES) atomicAdd(&deg[ecol[e]], 1);
}

// one-pass segment allocator: block scan + single atomic per block.
__global__ __launch_bounds__(256) void offsets_kernel(
    const int* __restrict__ deg, int* __restrict__ rowptr,
    int* __restrict__ cursor, int* __restrict__ gcount)
{
    const int t    = threadIdx.x;
    const int lane = t & 63;
    const int wid  = t >> 6;
    const int n    = blockIdx.x * 256 + t;
    const int d    = (n < N_NODES) ? deg[n] : 0;

    int x = d;
    #pragma unroll
    for (int off = 1; off < 64; off <<= 1) {
        int v = __shfl_up(x, off);
        x += (lane >= off) ? v : 0;
    }

    __shared__ int wsum[4];
    __shared__ int wbase[4];
    __shared__ int bbase;
    if (lane == 63) wsum[wid] = x;
    __syncthreads();
    if (t == 0) {
        int b = 0;
        #pragma unroll
        for (int w = 0; w < 4; ++w) { wbase[w] = b; b += wsum[w]; }
        bbase = atomicAdd(gcount, b);
    }
    __syncthreads();

    if (n < N_NODES) {
        const int excl = bbase + wbase[wid] + (x - d);
        rowptr[n] = excl;
        cursor[n] = excl;
    }
}

__global__ __launch_bounds__(256) void scatter_kernel(
    const int* __restrict__ erow, const int* __restrict__ ecol,
    int* __restrict__ cursor, int* __restrict__ csr_src)
{
    const int e = blockIdx.x * 256 + threadIdx.x;
    if (e < N_EDGES) {
        const int pos = atomicAdd(&cursor[ecol[e]], 1);
        csr_src[pos] = erow[e];
    }
}

// -------------------- hop 1: gather; M1/Kf1 stored bf16 --------------------
__global__ __launch_bounds__(256) void hop1_gather(
    const int* __restrict__ csr_src, const int* __restrict__ rowptr,
    const int* __restrict__ deg,
    const float* __restrict__ Q, const float* __restrict__ Kf0,
    const float* __restrict__ V0,
    __hip_bfloat16* __restrict__ Kf1, unsigned* __restrict__ M1,
    float* __restrict__ H1, float* __restrict__ Cd1)
{
    const int sub  = threadIdx.x >> 6;
    const int lane = threadIdx.x & 63;
    const int n    = blockIdx.x * 4 + sub;
    if (n >= N_NODES) return;
    const int h = lane >> 4;
    const int r = lane & 15;

    const float q = Q[(size_t)n * HID + lane];
    float accM[C_CLS];
    #pragma unroll
    for (int j = 0; j < C_CLS; ++j) accM[j] = 0.0f;
    float accK = 0.0f, accH = 0.0f, accA = 0.0f;

    const int beg = rowptr[n];
    const int d   = deg[n];
    for (int e = 0; e < d; ++e) {
        const int s = csr_src[beg + e];
        const float kf = Kf0[(size_t)s * HID + lane];
        accK += kf;
        float p = q * kf;
        p += __shfl_xor(p, 1);
        p += __shfl_xor(p, 2);
        p += __shfl_xor(p, 4);
        p += __shfl_xor(p, 8);
        accA += p;
        const float* v = V0 + (size_t)s * HC + h * C_CLS;
        #pragma unroll
        for (int j = 0; j < C_CLS; ++j) {
            const float vj = v[j];
            accM[j] += kf * vj;
            accH = (j == r) ? (accH + p * vj) : accH;
        }
    }

    Kf1[(size_t)n * HID + lane] = __float2bfloat16(accK);
    unsigned* m = M1 + (size_t)n * M_DW;
    #pragma unroll
    for (int j2 = 0; j2 < C_CLS / 2; ++j2)
        m[j2 * HID + lane] = pack_bf16x2(accM[2 * j2], accM[2 * j2 + 1]);
    if (r == 0)     Cd1[(size_t)n * HEADS + h] = accA;
    if (r < C_CLS)  H1 [(size_t)n * HC + h * C_CLS + r] = accH;
}

// -------------------- hop 2: gather; M2/Kf2 summed in registers --------------------
__global__ __launch_bounds__(256) void hop2_gather(
    const int* __restrict__ csr_src, const int* __restrict__ rowptr,
    const int* __restrict__ deg,
    const float* __restrict__ Q, const __hip_bfloat16* __restrict__ Kf1,
    const unsigned* __restrict__ M1,
    float* __restrict__ H2, float* __restrict__ Cd2)
{
    const int sub  = threadIdx.x >> 6;
    const int lane = threadIdx.x & 63;
    const int n    = blockIdx.x * 4 + sub;
    if (n >= N_NODES) return;
    const int h = lane >> 4;
    const int r = lane & 15;

    const float q = Q[(size_t)n * HID + lane];
    float accM[C_CLS];
    #pragma unroll
    for (int j = 0; j < C_CLS; ++j) accM[j] = 0.0f;
    float accK = 0.0f;

    const int beg = rowptr[n];
    const int d   = deg[n];
    for (int e = 0; e < d; ++e) {
        const int s = csr_src[beg + e];
        accK += __bfloat162float(Kf1[(size_t)s * HID + lane]);
        const unsigned* m = M1 + (size_t)s * M_DW;
        #pragma unroll
        for (int j2 = 0; j2 < C_CLS / 2; ++j2) {
            float a, b;
            unpack_bf16x2(m[j2 * HID + lane], a, b);
            accM[2 * j2]     += a;
            accM[2 * j2 + 1] += b;
        }
    }

    float pc = q * accK;
    pc += __shfl_xor(pc, 1);
    pc += __shfl_xor(pc, 2);
    pc += __shfl_xor(pc, 4);
    pc += __shfl_xor(pc, 8);
    if (r == 0) Cd2[(size_t)n * HEADS + h] = pc;

    float pj[C_CLS];
    #pragma unroll
    for (int j = 0; j < C_CLS; ++j) {
        pj[j] = q * accM[j];
        pj[j] += __shfl_xor(pj[j], 1);
        pj[j] += __shfl_xor(pj[j], 2);
        pj[j] += __shfl_xor(pj[j], 4);
        pj[j] += __shfl_xor(pj[j], 8);
    }
    if (r < C_CLS) {
        float val = 0.0f;
        #pragma unroll
        for (int j = 0; j < C_CLS; ++j) val = (r == j) ? pj[j] : val;
        H2[(size_t)n * HC + h * C_CLS + r] = val;
    }
}

// -------------------- combine + output projection --------------------
__global__ __launch_bounds__(256) void combine_kernel(
    const float* __restrict__ V0,
    const float* __restrict__ H1, const float* __restrict__ Cd1,
    const float* __restrict__ H2, const float* __restrict__ Cd2,
    const float* __restrict__ hopwise, const float* __restrict__ headwise,
    const float* __restrict__ W_out, const float* __restrict__ b_out,
    float* __restrict__ out)
{
    const int n = blockIdx.x * blockDim.x + threadIdx.x;
    if (n >= N_NODES) return;

    float hv[HEADS][2];
    float m0 = -1e30f, m1 = -1e30f;
    #pragma unroll
    for (int h = 0; h < HEADS; ++h) {
        hv[h][0] = headwise[h * 2 + 0];
        hv[h][1] = headwise[h * 2 + 1];
        m0 = fmaxf(m0, hv[h][0]);
        m1 = fmaxf(m1, hv[h][1]);
    }
    float s0 = 0.0f, s1 = 0.0f;
    float e0[HEADS], e1[HEADS];
    #pragma unroll
    for (int h = 0; h < HEADS; ++h) {
        e0[h] = expf(hv[h][0] - m0); s0 += e0[h];
        e1[h] = expf(hv[h][1] - m1); s1 += e1[h];
    }
    const float hw0 = hopwise[0];
    float g1[HEADS], g2[HEADS];
    #pragma unroll
    for (int h = 0; h < HEADS; ++h) {
        g1[h] = hopwise[1] * e0[h] / s0;
        g2[h] = hopwise[2] * e1[h] / s1;
    }

    float hidden[HC];
    #pragma unroll
    for (int h = 0; h < HEADS; ++h) {
        const float icd1 = 1.0f / (Cd1[(size_t)n * HEADS + h] + CST);
        const float icd2 = 1.0f / (Cd2[(size_t)n * HEADS + h] + CST);
        #pragma unroll
        for (int j = 0; j < C_CLS; ++j) {
            const int idx = h * C_CLS + j;
            hidden[idx] = hw0 * V0[(size_t)n * HC + idx]
                        + g1[h] * H1[(size_t)n * HC + idx] * icd1
                        + g2[h] * H2[(size_t)n * HC + idx] * icd2;
        }
    }

    #pragma unroll
    for (int c = 0; c < C_CLS; ++c) {
        float acc = b_out[c];
        const float* w = W_out + c * HC;
        #pragma unroll
        for (int k = 0; k < HC; ++k) acc += w[k] * hidden[k];
        out[(size_t)n * C_CLS + c] = acc;
    }
}

// -------------------- launch --------------------
extern "C" void kernel_launch(void* const* d_in, const int* in_sizes, int n_in,
                              void* d_out, int out_size, void* d_ws, size_t ws_size,
                              hipStream_t stream)
{
    const float* feat     = (const float*)d_in[0];
    const int*   eidx     = (const int*)  d_in[1];
    const float* W_in     = (const float*)d_in[2];
    const float* b_in     = (const float*)d_in[3];
    const float* W_q      = (const float*)d_in[4];
    const float* b_q      = (const float*)d_in[5];
    const float* W_k      = (const float*)d_in[6];
    const float* b_k      = (const float*)d_in[7];
    const float* W_v      = (const float*)d_in[8];
    const float* b_v      = (const float*)d_in[9];
    const float* W_out    = (const float*)d_in[10];
    const float* b_out    = (const float*)d_in[11];
    const float* hopwise  = (const float*)d_in[12];
    const float* headwise = (const float*)d_in[13];
    float* out = (float*)d_out;

    const int* erow = eidx;
    const int* ecol = eidx + N_EDGES;

    float* ws = (float*)d_ws;
    size_t off = 0;
    float* Q    = ws + off; off += (size_t)N_NODES * HID;
    float* Kf0  = ws + off; off += (size_t)N_NODES * HID;
    float* V0   = ws + off; off += (size_t)N_NODES * HC;
    __hip_bfloat16* Kf1 = (__hip_bfloat16*)(ws + off); off += (size_t)N_NODES * HID / 2;
    unsigned* M1 = (unsigned*)(ws + off); off += (size_t)N_NODES * M_DW;
    float* H1   = ws + off; off += (size_t)N_NODES * HC;
    float* Cd1  = ws + off; off += (size_t)N_NODES * HEADS;
    float* H2   = ws + off; off += (size_t)N_NODES * HC;
    float* Cd2  = ws + off; off += (size_t)N_NODES * HEADS;
    int* iws = (int*)(ws + off);
    int* deg     = iws;                     // N
    int* gcount  = iws + N_NODES;           // 1
    int* rowptr  = iws + N_NODES + 1;       // N
    int* cursor  = iws + 2 * N_NODES + 1;   // N
    int* csr_src = iws + 3 * N_NODES + 1;   // E

    hipMemsetAsync(deg, 0, (N_NODES + 1) * sizeof(int), stream);

    proj_kernel<<<(N_NODES + PTILE - 1) / PTILE, 512, 0, stream>>>(
        feat, W_in, b_in, W_q, b_q, W_k, b_k, W_v, b_v, Q, Kf0, V0);

    hist_kernel<<<(N_EDGES + 255) / 256, 256, 0, stream>>>(ecol, deg);
    offsets_kernel<<<(N_NODES + 255) / 256, 256, 0, stream>>>(deg, rowptr, cursor, gcount);
    scatter_kernel<<<(N_EDGES + 255) / 256, 256, 0, stream>>>(erow, ecol, cursor, csr_src);

    hop1_gather<<<(N_NODES + 3) / 4, 256, 0, stream>>>(
        csr_src, rowptr, deg, Q, Kf0, V0, Kf1, M1, H1, Cd1);

    hop2_gather<<<(N_NODES + 3) / 4, 256, 0, stream>>>(
        csr_src, rowptr, deg, Q, Kf1, M1, H2, Cd2);

    combine_kernel<<<(N_NODES + 255) / 256, 256, 0, stream>>>(
        V0, H1, Cd1, H2, Cd2, hopwise, headwise, W_out, b_out, out);
}